// Round 12
// baseline (265.178 us; speedup 1.0000x reference)
//
#include <hip/hip_runtime.h>
#include <hip/hip_bf16.h>
#include <hip/hip_cooperative_groups.h>
#include <stdint.h>

namespace cg = cooperative_groups;

#define K_DIM 4096
#define NKT   (K_DIM / 128)   // 32 K-tiles of BK=128 (i8)

typedef __attribute__((ext_vector_type(4))) float f32x4;
typedef __attribute__((ext_vector_type(4))) int i32x4;

#define GLOAD_LDS16(g, l)                                                        \
  __builtin_amdgcn_global_load_lds(                                              \
      (const __attribute__((address_space(1))) void*)(g),                        \
      (__attribute__((address_space(3))) void*)(l), 16, 0, 0)

// ---------------- gamma = mean(|W|): deterministic 2-stage reduction ----------
__global__ void absum_partial(const float* __restrict__ W,
                              float* __restrict__ partials, int n) {
  int tid = blockIdx.x * blockDim.x + threadIdx.x;
  int stride = gridDim.x * blockDim.x;
  const f32x4* W4 = (const f32x4*)W;
  int n4 = n >> 2;
  float s = 0.f;
  for (int i = tid; i < n4; i += stride) {
    f32x4 v = W4[i];
    s += fabsf(v[0]) + fabsf(v[1]) + fabsf(v[2]) + fabsf(v[3]);
  }
#pragma unroll
  for (int off = 32; off > 0; off >>= 1) s += __shfl_down(s, off, 64);
  __shared__ float wsum[4];
  if ((threadIdx.x & 63) == 0) wsum[threadIdx.x >> 6] = s;
  __syncthreads();
  if (threadIdx.x == 0)
    partials[blockIdx.x] = wsum[0] + wsum[1] + wsum[2] + wsum[3];
}

__global__ void gamma_finalize(const float* __restrict__ partials,
                               float* __restrict__ gamma, float inv_n) {
  __shared__ float sm[256];
  int t = threadIdx.x;
  sm[t] = partials[t] + partials[t + 256] + partials[t + 512] + partials[t + 768];
  __syncthreads();
  for (int off = 128; off > 0; off >>= 1) {
    if (t < off) sm[t] += sm[t + off];
    __syncthreads();
  }
  if (t == 0) gamma[0] = sm[0] * inv_n;
}

// ---------------- W -> ternary i8 (exact {-1,0,1}) ----------------------------
__global__ void quantize_w_i8(const float* __restrict__ W,
                              signed char* __restrict__ Wq,
                              const float* __restrict__ gamma_p, int n) {
  float g = gamma_p[0];
  float safe = (g == 0.f) ? 1.f : g;
  int tid = blockIdx.x * blockDim.x + threadIdx.x;
  int stride = gridDim.x * blockDim.x;
  const f32x4* W4 = (const f32x4*)W;
  int n4 = n >> 2;
  int* out = (int*)Wq;
  for (int i = tid; i < n4; i += stride) {
    f32x4 v = W4[i];
    int b0, b1, b2, b3;
    float t0 = rintf(v[0] / safe);
    float t1 = rintf(v[1] / safe);
    float t2 = rintf(v[2] / safe);
    float t3 = rintf(v[3] / safe);
    b0 = (t0 >= 0.5f) ? 1 : (t0 <= -0.5f ? -1 : 0);
    b1 = (t1 >= 0.5f) ? 1 : (t1 <= -0.5f ? -1 : 0);
    b2 = (t2 >= 0.5f) ? 1 : (t2 <= -0.5f ? -1 : 0);
    b3 = (t3 >= 0.5f) ? 1 : (t3 <= -0.5f ? -1 : 0);
    out[i] = (b0 & 255) | ((b1 & 255) << 8) | ((b2 & 255) << 16) |
             ((b3 & 255) << 24);
  }
}

// ------- fused cooperative: absum -> grid.sync -> gamma -> quantize W ---------
// Bit-identical arithmetic to the 3-kernel path: same partial order, same
// sum*inv_n, same rintf(v/safe) ternary. Second W pass hits L3 (64MiB just
// read, L3=256MiB) instead of HBM. Grid 1024x256 co-resident (<= 8 blk/CU).
__global__ __launch_bounds__(256)
void fused_gamma_quantw(const float* __restrict__ W,
                        signed char* __restrict__ Wq,
                        float* __restrict__ partials,
                        float* __restrict__ gamma_out,
                        float inv_n, int n) {
  int tid = blockIdx.x * blockDim.x + threadIdx.x;
  int stride = gridDim.x * blockDim.x;
  const f32x4* W4 = (const f32x4*)W;
  int n4 = n >> 2;
  float s = 0.f;
  for (int i = tid; i < n4; i += stride) {
    f32x4 v = W4[i];
    s += fabsf(v[0]) + fabsf(v[1]) + fabsf(v[2]) + fabsf(v[3]);
  }
#pragma unroll
  for (int off = 32; off > 0; off >>= 1) s += __shfl_down(s, off, 64);
  __shared__ float wsum[4];
  if ((threadIdx.x & 63) == 0) wsum[threadIdx.x >> 6] = s;
  __syncthreads();
  if (threadIdx.x == 0)
    partials[blockIdx.x] = wsum[0] + wsum[1] + wsum[2] + wsum[3];
  cg::this_grid().sync();
  // every block reduces the 1024 partials in the same fixed order (4KB, L2-hot)
  __shared__ float sm[256];
  int t = threadIdx.x;
  sm[t] = partials[t] + partials[t + 256] + partials[t + 512] + partials[t + 768];
  __syncthreads();
  for (int off = 128; off > 0; off >>= 1) {
    if (t < off) sm[t] += sm[t + off];
    __syncthreads();
  }
  float g = sm[0] * inv_n;
  if (blockIdx.x == 0 && t == 0) gamma_out[0] = g;
  float safe = (g == 0.f) ? 1.f : g;
  int* out = (int*)Wq;
  for (int i = tid; i < n4; i += stride) {
    f32x4 v = W4[i];
    int b0, b1, b2, b3;
    float t0 = rintf(v[0] / safe);
    float t1 = rintf(v[1] / safe);
    float t2 = rintf(v[2] / safe);
    float t3 = rintf(v[3] / safe);
    b0 = (t0 >= 0.5f) ? 1 : (t0 <= -0.5f ? -1 : 0);
    b1 = (t1 >= 0.5f) ? 1 : (t1 <= -0.5f ? -1 : 0);
    b2 = (t2 >= 0.5f) ? 1 : (t2 <= -0.5f ? -1 : 0);
    b3 = (t3 >= 0.5f) ? 1 : (t3 <= -0.5f ? -1 : 0);
    out[i] = (b0 & 255) | ((b1 & 255) << 8) | ((b2 & 255) << 16) |
             ((b3 & 255) << 24);
  }
}

// -------- x fp32 -> i8 with per-row scale: x_q = rint(127*x/rowmax) -----------
__global__ __launch_bounds__(256)
void quant_x_i8(const float* __restrict__ X, signed char* __restrict__ Xq,
                float* __restrict__ xscale) {
  int row = blockIdx.x;
  int t = threadIdx.x;
  const f32x4* xr = (const f32x4*)(X + (size_t)row * K_DIM);
  f32x4 v0 = xr[t], v1 = xr[t + 256], v2 = xr[t + 512], v3 = xr[t + 768];
  float mx = 0.f;
#define AMAX4(V)                                                               \
  mx = fmaxf(mx, fmaxf(fmaxf(fabsf(V[0]), fabsf(V[1])),                        \
                       fmaxf(fabsf(V[2]), fabsf(V[3]))));
  AMAX4(v0) AMAX4(v1) AMAX4(v2) AMAX4(v3)
#undef AMAX4
#pragma unroll
  for (int off = 32; off > 0; off >>= 1) mx = fmaxf(mx, __shfl_down(mx, off, 64));
  __shared__ float wmx[4];
  if ((t & 63) == 0) wmx[t >> 6] = mx;
  __syncthreads();
  float rmax = fmaxf(fmaxf(wmx[0], wmx[1]), fmaxf(wmx[2], wmx[3]));
  float inv = (rmax > 0.f) ? 127.0f / rmax : 0.f;
  if (t == 0) xscale[row] = (rmax > 0.f) ? rmax / 127.0f : 0.f;
  int* out = (int*)(Xq + (size_t)row * K_DIM);
#define PACK(V, IDX)                                                           \
  {                                                                            \
    int c0 = __float2int_rn(V[0] * inv), c1 = __float2int_rn(V[1] * inv);      \
    int c2 = __float2int_rn(V[2] * inv), c3 = __float2int_rn(V[3] * inv);      \
    out[IDX] = (c0 & 255) | ((c1 & 255) << 8) | ((c2 & 255) << 16) |           \
               ((c3 & 255) << 24);                                             \
  }
  PACK(v0, t) PACK(v1, t + 256) PACK(v2, t + 512) PACK(v3, t + 768)
#undef PACK
}

// -------- 256x256 i8 GEMM: R9 verbatim (proven best: 146us, 0 conflicts) ------
// out[r][c] = gamma * xscale[r] * sum_k Wq[c][k] * Xq[r][k]  (exact i32 dot)
// 512 thr = 8 waves (2Mx4N), wave out 128x64 = 8x4 frags mfma_i32_16x16x64_i8.
// K-tile BK=128. LDS per matrix [2 buf][2 half][256 rows][64 B] = 64KB;
// A+B = 128KiB; tile kt in buf kt&1. 4 phases/tile: {4|8 ds_read_b128;
// stage 1 half (2 gload_lds); BAR; lgkm(0); prio1; 16 MFMA; prio0; BAR}.
// Stage stream: ph0 A-ks1(kt+1)->buf^1; ph1 B-ks0(kt+2); ph2 A-ks0(kt+2);
// ph3 B-ks1(kt+2)+vmcnt(6). Ledger proven over 3 passing rounds.
// Swizzle both-sides (rule 21): LDS[row][cphys] = global[row][cphys ^
// ((row>>1)&3)]; reads fold the XOR into the lane base.
__global__ __launch_bounds__(512, 2)
void gemm_i8_t(const signed char* __restrict__ A,
               const signed char* __restrict__ Bq,
               float* __restrict__ C,
               const float* __restrict__ gamma_p,
               const float* __restrict__ xscale, int M, int N) {
  __shared__ __align__(16) signed char Ab[2][2][256][64];  // 64 KiB
  __shared__ __align__(16) signed char Bb[2][2][256][64];  // 64 KiB

  int ntN = N >> 8;
  int bid = blockIdx.x;
  int swz = (bid & 7) * (gridDim.x >> 3) + (bid >> 3);  // nwg % 8 == 0
  int tm = swz / ntN, tn = swz % ntN;

  int t = threadIdx.x;
  int lane = t & 63;
  int wid = t >> 6;
  int wr = wid >> 2, wc = wid & 3;   // 2 x 4 wave grid, wave out 128x64
  int lr = lane & 15;
  int cphys = (lane >> 4) ^ ((lr >> 1) & 3);   // swizzled 16B chunk in 64B half

  const signed char* aG = A + (size_t)tm * 256 * K_DIM;
  const signed char* bG = Bq + (size_t)tn * 256 * K_DIM;

  int srow = t >> 2;
  int sclog = (t & 3) ^ ((t >> 3) & 3);
  const signed char* aSg = aG + (size_t)srow * K_DIM + (sclog << 4);
  const signed char* bSg = bG + (size_t)srow * K_DIM + (sclog << 4);
  char* aSl = (char*)Ab + t * 16;
  char* bSl = (char*)Bb + t * 16;

  const signed char* aRd = &Ab[0][0][0][0] + (wr * 128 + lr) * 64 + cphys * 16;
  const signed char* bRd = &Bb[0][0][0][0] + (wc * 64 + lr) * 64 + cphys * 16;

  i32x4 acc[8][4];
#pragma unroll
  for (int m = 0; m < 8; ++m)
#pragma unroll
    for (int n = 0; n < 4; ++n) acc[m][n] = (i32x4)(0);

#define STAGE_A(J, BUF, KS)                                                    \
  { GLOAD_LDS16(aSg + (size_t)(J) * 128 + (KS) * 64,                           \
                aSl + (BUF) * 32768 + (KS) * 16384);                           \
    GLOAD_LDS16(aSg + (size_t)(J) * 128 + (KS) * 64 + (size_t)128 * K_DIM,     \
                aSl + (BUF) * 32768 + (KS) * 16384 + 8192); }
#define STAGE_B(J, BUF, KS)                                                    \
  { GLOAD_LDS16(bSg + (size_t)(J) * 128 + (KS) * 64,                           \
                bSl + (BUF) * 32768 + (KS) * 16384);                           \
    GLOAD_LDS16(bSg + (size_t)(J) * 128 + (KS) * 64 + (size_t)128 * K_DIM,     \
                bSl + (BUF) * 32768 + (KS) * 16384 + 8192); }
#define BAR() __builtin_amdgcn_s_barrier()
#define VMC(NN) asm volatile("s_waitcnt vmcnt(" #NN ")" ::: "memory")
#define LGKM0() asm volatile("s_waitcnt lgkmcnt(0)" ::: "memory")
#define SB0() __builtin_amdgcn_sched_barrier(0)
#define RD_B(BUF, KS)                                                          \
  { _Pragma("unroll") for (int n = 0; n < 4; ++n)                              \
      bfr[n] = *(const i32x4*)(bRd + (BUF) * 32768 + (KS) * 16384 + n * 1024); }
#define RD_A(BUF, KS, MH)                                                      \
  { _Pragma("unroll") for (int m = 0; m < 4; ++m)                              \
      af[m] = *(const i32x4*)(aRd + (BUF) * 32768 + (KS) * 16384 +             \
                              (MH) * 4096 + m * 1024); }
#define MFMA16(MH)                                                             \
  { __builtin_amdgcn_s_setprio(1);                                             \
    _Pragma("unroll") for (int m = 0; m < 4; ++m)                              \
      _Pragma("unroll") for (int n = 0; n < 4; ++n)                            \
        acc[(MH) * 4 + m][n] = __builtin_amdgcn_mfma_i32_16x16x64_i8(          \
            af[m], bfr[n], acc[(MH) * 4 + m][n], 0, 0, 0);                     \
    __builtin_amdgcn_s_setprio(0); }

#define TILE(KT, BUF, DO_S1, DO_S2, VEND)                                      \
  {                                                                            \
    RD_B(BUF, 0); RD_A(BUF, 0, 0);                                             \
    if (DO_S1) STAGE_A((KT) + 1, (BUF) ^ 1, 1);                                \
    BAR(); LGKM0(); SB0();                                                     \
    MFMA16(0);                                                                 \
    BAR();                                                                     \
    RD_A(BUF, 0, 1);                                                           \
    if (DO_S2) STAGE_B((KT) + 2, BUF, 0);                                      \
    BAR(); LGKM0(); SB0();                                                     \
    MFMA16(1);                                                                 \
    BAR();                                                                     \
    RD_B(BUF, 1); RD_A(BUF, 1, 0);                                             \
    if (DO_S2) STAGE_A((KT) + 2, BUF, 0);                                      \
    BAR(); LGKM0(); SB0();                                                     \
    MFMA16(0);                                                                 \
    BAR();                                                                     \
    RD_A(BUF, 1, 1);                                                           \
    if (DO_S2) STAGE_B((KT) + 2, BUF, 1);                                      \
    BAR(); LGKM0(); SB0();                                                     \
    MFMA16(1);                                                                 \
    VEND; SB0();                                                               \
    BAR();                                                                     \
  }

  STAGE_B(0, 0, 0); STAGE_A(0, 0, 0); STAGE_B(0, 0, 1); STAGE_A(0, 0, 1);
  STAGE_B(1, 1, 0); STAGE_A(1, 1, 0); STAGE_B(1, 1, 1);
  VMC(6); SB0();
  BAR();

  i32x4 af[4], bfr[4];
  for (int i = 0; i < 15; ++i) {
    int kt = i << 1;
    TILE(kt, 0, 1, 1, VMC(6));
    TILE(kt + 1, 1, 1, 1, VMC(6));
  }
  TILE(30, 0, 1, 0, VMC(0));
  TILE(31, 1, 0, 0, (void)0);

  float g = gamma_p[0];
  int crow = (lane >> 4) << 2;   // C/D: col = lane&15, row = (lane>>4)*4 + reg
  size_t row0 = (size_t)tm * 256 + wr * 128 + crow;
  int col0 = tn * 256 + wc * 64 + lr;
#pragma unroll
  for (int m = 0; m < 8; ++m) {
#pragma unroll
    for (int j = 0; j < 4; ++j) {
      size_t row = row0 + m * 16 + j;
      float sc = g * xscale[row];
      float* cp = C + row * (size_t)N + col0;
#pragma unroll
      for (int n = 0; n < 4; ++n) cp[n * 16] = (float)acc[m][n][j] * sc;
    }
  }
#undef STAGE_A
#undef STAGE_B
#undef BAR
#undef VMC
#undef LGKM0
#undef SB0
#undef RD_B
#undef RD_A
#undef MFMA16
#undef TILE
}

// ---------------- naive fallback (only if ws too small / odd shapes) ----------
__global__ void naive_bitlinear(const float* __restrict__ X,
                                const float* __restrict__ W,
                                float* __restrict__ out,
                                const float* __restrict__ gamma_p, int M, int N) {
  int col = blockIdx.x * blockDim.x + threadIdx.x;
  int row = blockIdx.y;
  if (col >= N || row >= M) return;
  float g = gamma_p[0];
  float safe = (g == 0.f) ? 1.f : g;
  const float* x = X + (size_t)row * K_DIM;
  const float* w = W + (size_t)col * K_DIM;
  float s = 0.f;
  for (int k = 0; k < K_DIM; ++k) {
    float qv = fminf(fmaxf(rintf(w[k] / safe), -1.f), 1.f);
    s += x[k] * qv;
  }
  out[(size_t)row * N + col] = s * g;
}

extern "C" void kernel_launch(void* const* d_in, const int* in_sizes, int n_in,
                              void* d_out, int out_size, void* d_ws,
                              size_t ws_size, hipStream_t stream) {
  const float* x = (const float*)d_in[0];
  const float* w = (const float*)d_in[1];
  float* out = (float*)d_out;
  int xn = in_sizes[0];   // B*S*D_IN = 33554432
  int wn = in_sizes[1];   // D_OUT*D_IN = 16777216
  int M = xn / K_DIM;     // 8192
  int N = wn / K_DIM;     // 4096

  char* ws = (char*)d_ws;
  float* partials = (float*)ws;                        // 1024 floats
  float* gamma = (float*)(ws + 4096);                  // 1 float
  float* xscale = (float*)(ws + 8192);                 // M floats (32 KiB)
  signed char* Wq = (signed char*)(ws + 8192 + 32768); // N*K i8
  signed char* Xq = Wq + (size_t)wn;                   // M*K i8
  size_t need = 8192 + 32768 + (size_t)wn + (size_t)xn;

  float inv_n = 1.0f / (float)wn;

  if (ws_size >= need && (M & 255) == 0 && (N & 255) == 0) {
    // fused cooperative prologue for W (bit-identical math); fallback = 3 kernels
    void* wq_v = (void*)Wq;
    void* w_v = (void*)w;
    void* args[] = {&w_v, &wq_v, (void*)&partials, (void*)&gamma,
                    (void*)&inv_n, (void*)&wn};
    hipError_t ce = hipLaunchCooperativeKernel(
        (const void*)fused_gamma_quantw, dim3(1024), dim3(256), args, 0, stream);
    if (ce != hipSuccess) {
      absum_partial<<<1024, 256, 0, stream>>>(w, partials, wn);
      gamma_finalize<<<1, 256, 0, stream>>>(partials, gamma, inv_n);
      quantize_w_i8<<<2048, 256, 0, stream>>>(w, Wq, gamma, wn);
    }
    quant_x_i8<<<M, 256, 0, stream>>>(x, Xq, xscale);
    int nwg = (M >> 8) * (N >> 8);   // 32 * 16 = 512
    gemm_i8_t<<<nwg, 512, 0, stream>>>(Xq, Wq, out, gamma, xscale, M, N);
  } else {
    absum_partial<<<1024, 256, 0, stream>>>(w, partials, wn);
    gamma_finalize<<<1, 256, 0, stream>>>(partials, gamma, inv_n);
    dim3 grid((N + 255) / 256, M);
    naive_bitlinear<<<grid, 256, 0, stream>>>(x, w, out, gamma, M, N);
  }
}

// Round 13
// 195.608 us; speedup vs baseline: 1.3557x; 1.3557x over previous
//
#include <hip/hip_runtime.h>
#include <hip/hip_bf16.h>
#include <stdint.h>

#define K_DIM 4096
#define NKT   (K_DIM / 128)   // 32 K-tiles of BK=128 (i8)

typedef __attribute__((ext_vector_type(4))) float f32x4;
typedef __attribute__((ext_vector_type(4))) int i32x4;

#define GLOAD_LDS16(g, l)                                                        \
  __builtin_amdgcn_global_load_lds(                                              \
      (const __attribute__((address_space(1))) void*)(g),                        \
      (__attribute__((address_space(3))) void*)(l), 16, 0, 0)

// ---------------- gamma = mean(|W|): deterministic 2-stage reduction ----------
// Prologue is at HBM floor (measured ~51us vs 48us floor) — do not touch (R12).
__global__ void absum_partial(const float* __restrict__ W,
                              float* __restrict__ partials, int n) {
  int tid = blockIdx.x * blockDim.x + threadIdx.x;
  int stride = gridDim.x * blockDim.x;
  const f32x4* W4 = (const f32x4*)W;
  int n4 = n >> 2;
  float s = 0.f;
  for (int i = tid; i < n4; i += stride) {
    f32x4 v = W4[i];
    s += fabsf(v[0]) + fabsf(v[1]) + fabsf(v[2]) + fabsf(v[3]);
  }
#pragma unroll
  for (int off = 32; off > 0; off >>= 1) s += __shfl_down(s, off, 64);
  __shared__ float wsum[4];
  if ((threadIdx.x & 63) == 0) wsum[threadIdx.x >> 6] = s;
  __syncthreads();
  if (threadIdx.x == 0)
    partials[blockIdx.x] = wsum[0] + wsum[1] + wsum[2] + wsum[3];
}

__global__ void gamma_finalize(const float* __restrict__ partials,
                               float* __restrict__ gamma, float inv_n) {
  __shared__ float sm[256];
  int t = threadIdx.x;
  sm[t] = partials[t] + partials[t + 256] + partials[t + 512] + partials[t + 768];
  __syncthreads();
  for (int off = 128; off > 0; off >>= 1) {
    if (t < off) sm[t] += sm[t + off];
    __syncthreads();
  }
  if (t == 0) gamma[0] = sm[0] * inv_n;
}

// ---------------- W -> ternary i8 (exact {-1,0,1}) ----------------------------
__global__ void quantize_w_i8(const float* __restrict__ W,
                              signed char* __restrict__ Wq,
                              const float* __restrict__ gamma_p, int n) {
  float g = gamma_p[0];
  float safe = (g == 0.f) ? 1.f : g;
  int tid = blockIdx.x * blockDim.x + threadIdx.x;
  int stride = gridDim.x * blockDim.x;
  const f32x4* W4 = (const f32x4*)W;
  int n4 = n >> 2;
  int* out = (int*)Wq;
  for (int i = tid; i < n4; i += stride) {
    f32x4 v = W4[i];
    int b0, b1, b2, b3;
    float t0 = rintf(v[0] / safe);
    float t1 = rintf(v[1] / safe);
    float t2 = rintf(v[2] / safe);
    float t3 = rintf(v[3] / safe);
    b0 = (t0 >= 0.5f) ? 1 : (t0 <= -0.5f ? -1 : 0);
    b1 = (t1 >= 0.5f) ? 1 : (t1 <= -0.5f ? -1 : 0);
    b2 = (t2 >= 0.5f) ? 1 : (t2 <= -0.5f ? -1 : 0);
    b3 = (t3 >= 0.5f) ? 1 : (t3 <= -0.5f ? -1 : 0);
    out[i] = (b0 & 255) | ((b1 & 255) << 8) | ((b2 & 255) << 16) |
             ((b3 & 255) << 24);
  }
}

// -------- x fp32 -> i8 with per-row scale: x_q = rint(127*x/rowmax) -----------
__global__ __launch_bounds__(256)
void quant_x_i8(const float* __restrict__ X, signed char* __restrict__ Xq,
                float* __restrict__ xscale) {
  int row = blockIdx.x;
  int t = threadIdx.x;
  const f32x4* xr = (const f32x4*)(X + (size_t)row * K_DIM);
  f32x4 v0 = xr[t], v1 = xr[t + 256], v2 = xr[t + 512], v3 = xr[t + 768];
  float mx = 0.f;
#define AMAX4(V)                                                               \
  mx = fmaxf(mx, fmaxf(fmaxf(fabsf(V[0]), fabsf(V[1])),                        \
                       fmaxf(fabsf(V[2]), fabsf(V[3]))));
  AMAX4(v0) AMAX4(v1) AMAX4(v2) AMAX4(v3)
#undef AMAX4
#pragma unroll
  for (int off = 32; off > 0; off >>= 1) mx = fmaxf(mx, __shfl_down(mx, off, 64));
  __shared__ float wmx[4];
  if ((t & 63) == 0) wmx[t >> 6] = mx;
  __syncthreads();
  float rmax = fmaxf(fmaxf(wmx[0], wmx[1]), fmaxf(wmx[2], wmx[3]));
  float inv = (rmax > 0.f) ? 127.0f / rmax : 0.f;
  if (t == 0) xscale[row] = (rmax > 0.f) ? rmax / 127.0f : 0.f;
  int* out = (int*)(Xq + (size_t)row * K_DIM);
#define PACK(V, IDX)                                                           \
  {                                                                            \
    int c0 = __float2int_rn(V[0] * inv), c1 = __float2int_rn(V[1] * inv);      \
    int c2 = __float2int_rn(V[2] * inv), c3 = __float2int_rn(V[3] * inv);      \
    out[IDX] = (c0 & 255) | ((c1 & 255) << 8) | ((c2 & 255) << 16) |           \
               ((c3 & 255) << 24);                                             \
  }
  PACK(v0, t) PACK(v1, t + 256) PACK(v2, t + 512) PACK(v3, t + 768)
#undef PACK
}

// -------- 256x256 i8 GEMM: R9 verbatim (best known: ~146us, 0 conflicts) ------
// out[r][c] = gamma * xscale[r] * sum_k Wq[c][k] * Xq[r][k]  (exact i32 dot)
// 512 thr = 8 waves (2Mx4N), wave out 128x64 = 8x4 frags mfma_i32_16x16x64_i8.
// K-tile BK=128. LDS per matrix [2 buf][2 half][256 rows][64 B] = 64KB;
// A+B = 128KiB; tile kt in buf kt&1. 4 phases/tile: {4|8 ds_read_b128;
// stage 1 half (2 gload_lds); BAR; lgkm(0); prio1; 16 MFMA; prio0; BAR}.
// Stage stream: ph0 A-ks1(kt+1)->buf^1; ph1 B-ks0(kt+2); ph2 A-ks0(kt+2);
// ph3 B-ks1(kt+2)+vmcnt(6). Ledger proven over 4 passing rounds.
// Swizzle both-sides (rule 21): LDS[row][cphys] = global[row][cphys ^
// ((row>>1)&3)]; staging permutes the GLOBAL chunk (LDS dest linear);
// reads fold the XOR into the lane base.
__global__ __launch_bounds__(512, 2)
void gemm_i8_t(const signed char* __restrict__ A,
               const signed char* __restrict__ Bq,
               float* __restrict__ C,
               const float* __restrict__ gamma_p,
               const float* __restrict__ xscale, int M, int N) {
  __shared__ __align__(16) signed char Ab[2][2][256][64];  // 64 KiB
  __shared__ __align__(16) signed char Bb[2][2][256][64];  // 64 KiB

  int ntN = N >> 8;
  int bid = blockIdx.x;
  int swz = (bid & 7) * (gridDim.x >> 3) + (bid >> 3);  // nwg % 8 == 0
  int tm = swz / ntN, tn = swz % ntN;

  int t = threadIdx.x;
  int lane = t & 63;
  int wid = t >> 6;
  int wr = wid >> 2, wc = wid & 3;   // 2 x 4 wave grid, wave out 128x64
  int lr = lane & 15;
  int cphys = (lane >> 4) ^ ((lr >> 1) & 3);   // swizzled 16B chunk in 64B half

  const signed char* aG = A + (size_t)tm * 256 * K_DIM;
  const signed char* bG = Bq + (size_t)tn * 256 * K_DIM;

  int srow = t >> 2;
  int sclog = (t & 3) ^ ((t >> 3) & 3);
  const signed char* aSg = aG + (size_t)srow * K_DIM + (sclog << 4);
  const signed char* bSg = bG + (size_t)srow * K_DIM + (sclog << 4);
  char* aSl = (char*)Ab + t * 16;
  char* bSl = (char*)Bb + t * 16;

  const signed char* aRd = &Ab[0][0][0][0] + (wr * 128 + lr) * 64 + cphys * 16;
  const signed char* bRd = &Bb[0][0][0][0] + (wc * 64 + lr) * 64 + cphys * 16;

  i32x4 acc[8][4];
#pragma unroll
  for (int m = 0; m < 8; ++m)
#pragma unroll
    for (int n = 0; n < 4; ++n) acc[m][n] = (i32x4)(0);

#define STAGE_A(J, BUF, KS)                                                    \
  { GLOAD_LDS16(aSg + (size_t)(J) * 128 + (KS) * 64,                           \
                aSl + (BUF) * 32768 + (KS) * 16384);                           \
    GLOAD_LDS16(aSg + (size_t)(J) * 128 + (KS) * 64 + (size_t)128 * K_DIM,     \
                aSl + (BUF) * 32768 + (KS) * 16384 + 8192); }
#define STAGE_B(J, BUF, KS)                                                    \
  { GLOAD_LDS16(bSg + (size_t)(J) * 128 + (KS) * 64,                           \
                bSl + (BUF) * 32768 + (KS) * 16384);                           \
    GLOAD_LDS16(bSg + (size_t)(J) * 128 + (KS) * 64 + (size_t)128 * K_DIM,     \
                bSl + (BUF) * 32768 + (KS) * 16384 + 8192); }
#define BAR() __builtin_amdgcn_s_barrier()
#define VMC(NN) asm volatile("s_waitcnt vmcnt(" #NN ")" ::: "memory")
#define LGKM0() asm volatile("s_waitcnt lgkmcnt(0)" ::: "memory")
#define SB0() __builtin_amdgcn_sched_barrier(0)
#define RD_B(BUF, KS)                                                          \
  { _Pragma("unroll") for (int n = 0; n < 4; ++n)                              \
      bfr[n] = *(const i32x4*)(bRd + (BUF) * 32768 + (KS) * 16384 + n * 1024); }
#define RD_A(BUF, KS, MH)                                                      \
  { _Pragma("unroll") for (int m = 0; m < 4; ++m)                              \
      af[m] = *(const i32x4*)(aRd + (BUF) * 32768 + (KS) * 16384 +             \
                              (MH) * 4096 + m * 1024); }
#define MFMA16(MH)                                                             \
  { __builtin_amdgcn_s_setprio(1);                                             \
    _Pragma("unroll") for (int m = 0; m < 4; ++m)                              \
      _Pragma("unroll") for (int n = 0; n < 4; ++n)                            \
        acc[(MH) * 4 + m][n] = __builtin_amdgcn_mfma_i32_16x16x64_i8(          \
            af[m], bfr[n], acc[(MH) * 4 + m][n], 0, 0, 0);                     \
    __builtin_amdgcn_s_setprio(0); }

#define TILE(KT, BUF, DO_S1, DO_S2, VEND)                                      \
  {                                                                            \
    RD_B(BUF, 0); RD_A(BUF, 0, 0);                                             \
    if (DO_S1) STAGE_A((KT) + 1, (BUF) ^ 1, 1);                                \
    BAR(); LGKM0(); SB0();                                                     \
    MFMA16(0);                                                                 \
    BAR();                                                                     \
    RD_A(BUF, 0, 1);                                                           \
    if (DO_S2) STAGE_B((KT) + 2, BUF, 0);                                      \
    BAR(); LGKM0(); SB0();                                                     \
    MFMA16(1);                                                                 \
    BAR();                                                                     \
    RD_B(BUF, 1); RD_A(BUF, 1, 0);                                             \
    if (DO_S2) STAGE_A((KT) + 2, BUF, 0);                                      \
    BAR(); LGKM0(); SB0();                                                     \
    MFMA16(0);                                                                 \
    BAR();                                                                     \
    RD_A(BUF, 1, 1);                                                           \
    if (DO_S2) STAGE_B((KT) + 2, BUF, 1);                                      \
    BAR(); LGKM0(); SB0();                                                     \
    MFMA16(1);                                                                 \
    VEND; SB0();                                                               \
    BAR();                                                                     \
  }

  STAGE_B(0, 0, 0); STAGE_A(0, 0, 0); STAGE_B(0, 0, 1); STAGE_A(0, 0, 1);
  STAGE_B(1, 1, 0); STAGE_A(1, 1, 0); STAGE_B(1, 1, 1);
  VMC(6); SB0();
  BAR();

  i32x4 af[4], bfr[4];
  for (int i = 0; i < 15; ++i) {
    int kt = i << 1;
    TILE(kt, 0, 1, 1, VMC(6));
    TILE(kt + 1, 1, 1, 1, VMC(6));
  }
  TILE(30, 0, 1, 0, VMC(0));
  TILE(31, 1, 0, 0, (void)0);

  float g = gamma_p[0];
  int crow = (lane >> 4) << 2;   // C/D: col = lane&15, row = (lane>>4)*4 + reg
  size_t row0 = (size_t)tm * 256 + wr * 128 + crow;
  int col0 = tn * 256 + wc * 64 + lr;
#pragma unroll
  for (int m = 0; m < 8; ++m) {
#pragma unroll
    for (int j = 0; j < 4; ++j) {
      size_t row = row0 + m * 16 + j;
      float sc = g * xscale[row];
      float* cp = C + row * (size_t)N + col0;
#pragma unroll
      for (int n = 0; n < 4; ++n) cp[n * 16] = (float)acc[m][n][j] * sc;
    }
  }
#undef STAGE_A
#undef STAGE_B
#undef BAR
#undef VMC
#undef LGKM0
#undef SB0
#undef RD_B
#undef RD_A
#undef MFMA16
#undef TILE
}

// ---------------- naive fallback (only if ws too small / odd shapes) ----------
__global__ void naive_bitlinear(const float* __restrict__ X,
                                const float* __restrict__ W,
                                float* __restrict__ out,
                                const float* __restrict__ gamma_p, int M, int N) {
  int col = blockIdx.x * blockDim.x + threadIdx.x;
  int row = blockIdx.y;
  if (col >= N || row >= M) return;
  float g = gamma_p[0];
  float safe = (g == 0.f) ? 1.f : g;
  const float* x = X + (size_t)row * K_DIM;
  const float* w = W + (size_t)col * K_DIM;
  float s = 0.f;
  for (int k = 0; k < K_DIM; ++k) {
    float qv = fminf(fmaxf(rintf(w[k] / safe), -1.f), 1.f);
    s += x[k] * qv;
  }
  out[(size_t)row * N + col] = s * g;
}

extern "C" void kernel_launch(void* const* d_in, const int* in_sizes, int n_in,
                              void* d_out, int out_size, void* d_ws,
                              size_t ws_size, hipStream_t stream) {
  const float* x = (const float*)d_in[0];
  const float* w = (const float*)d_in[1];
  float* out = (float*)d_out;
  int xn = in_sizes[0];   // B*S*D_IN = 33554432
  int wn = in_sizes[1];   // D_OUT*D_IN = 16777216
  int M = xn / K_DIM;     // 8192
  int N = wn / K_DIM;     // 4096

  char* ws = (char*)d_ws;
  float* partials = (float*)ws;                        // 1024 floats
  float* gamma = (float*)(ws + 4096);                  // 1 float
  float* xscale = (float*)(ws + 8192);                 // M floats (32 KiB)
  signed char* Wq = (signed char*)(ws + 8192 + 32768); // N*K i8
  signed char* Xq = Wq + (size_t)wn;                   // M*K i8
  size_t need = 8192 + 32768 + (size_t)wn + (size_t)xn;

  absum_partial<<<1024, 256, 0, stream>>>(w, partials, wn);
  gamma_finalize<<<1, 256, 0, stream>>>(partials, gamma, 1.0f / (float)wn);

  if (ws_size >= need && (M & 255) == 0 && (N & 255) == 0) {
    quantize_w_i8<<<2048, 256, 0, stream>>>(w, Wq, gamma, wn);
    quant_x_i8<<<M, 256, 0, stream>>>(x, Xq, xscale);
    int nwg = (M >> 8) * (N >> 8);   // 32 * 16 = 512
    gemm_i8_t<<<nwg, 512, 0, stream>>>(Xq, Wq, out, gamma, xscale, M, N);
  } else {
    dim3 grid((N + 255) / 256, M);
    naive_bitlinear<<<grid, 256, 0, stream>>>(x, w, out, gamma, M, N);
  }
}